// Round 5
// baseline (399.800 us; speedup 1.0000x reference)
//
#include <hip/hip_runtime.h>
#include <hip/hip_bf16.h>
#include <cstdint>
#include <cstddef>

#define T_TOK 4096
#define DIM   1024
#define IDIM  1024
#define NEXP  32
#define TOPK  4
#define MAXT  160            // max 128-row m-tiles
#define RPAD  (MAXT*128)     // 20480 padded rows max

#define GUP_ELEMS 67108864ull   // 32*2048*1024
#define ALL_ELEMS 100663296ull  // + 32*1024*1024
#define ROUTER_BLOCKS (T_TOK/4)               // 1024
#define CONV_BLOCKS   2048
#define CONV_STRIDE   ((size_t)CONV_BLOCKS*256*8)   // 4,194,304 elems
#define CONV_ITERS    24                      // ALL_ELEMS / CONV_STRIDE

typedef short sh8   __attribute__((ext_vector_type(8)));
typedef float f32x4 __attribute__((ext_vector_type(4)));

__device__ __forceinline__ short bf(float f) {
    union { float f; uint32_t u; } v; v.f = f;
    uint32_t r = (v.u + 0x7FFFu + ((v.u >> 16) & 1u)) >> 16;   // RNE
    return (short)r;
}
__device__ __forceinline__ float bf2f(short s) {
    union { uint32_t u; float f; } v; v.u = ((uint32_t)(uint16_t)s) << 16;
    return v.f;
}
__device__ __forceinline__ sh8 pack8(float4 a, float4 b) {
    sh8 r;
    r[0]=bf(a.x); r[1]=bf(a.y); r[2]=bf(a.z); r[3]=bf(a.w);
    r[4]=bf(b.x); r[5]=bf(b.y); r[6]=bf(b.z); r[7]=bf(b.w);
    return r;
}
__device__ __forceinline__ sh8 pack8v(f32x4 a, f32x4 b) {
    sh8 r;
    r[0]=bf(a[0]); r[1]=bf(a[1]); r[2]=bf(a[2]); r[3]=bf(a[3]);
    r[4]=bf(b[0]); r[5]=bf(b[1]); r[6]=bf(b[2]); r[7]=bf(b[3]);
    return r;
}
__device__ __forceinline__ f32x4 ntld(const float* p) {
    return __builtin_nontemporal_load(reinterpret_cast<const f32x4*>(p));
}
__device__ __forceinline__ void glds16(const void* g, const void* l) {
    __builtin_amdgcn_global_load_lds((const __attribute__((address_space(1))) void*)g,
                                     (__attribute__((address_space(3))) void*)l, 16, 0, 0);
}

// Per-block plan recompute: which expert owns m-tile `mt`; tile_start = first tile of e.
__device__ __forceinline__ int tile_expert(const int* __restrict__ cnt, int mt, int& tile_start) {
    int s = 0, e = -1, ts = 0;
    #pragma unroll
    for (int i = 0; i < NEXP; ++i) {
        int t = (cnt[i] + 127) >> 7;
        if (mt >= s && mt < s + t) { e = i; ts = s; }
        s += t;
    }
    tile_start = ts;
    return e;
}

// ---------------- Fat front kernel: router first, streaming convert behind ----------------
template<bool DO_CONV>
__global__ __launch_bounds__(256) void front_kernel(
    const float* __restrict__ X, const float* __restrict__ GW,
    const float* __restrict__ bias,
    const float* __restrict__ gup, const float* __restrict__ dp,
    short* __restrict__ wgu,               // wd contiguous after wgu
    int* __restrict__ topk_idx, float* __restrict__ topk_w,
    int* __restrict__ cnt, int* __restrict__ tlist_c, int* __restrict__ posmap)
{
    if (DO_CONV && blockIdx.x >= ROUTER_BLOCKS) {
        // streaming fp32->bf16 convert: grid-stride, 2-deep pipeline, NT loads
        int cb = (int)blockIdx.x - ROUTER_BLOCKS;
        size_t base = ((size_t)cb * 256 + threadIdx.x) * 8;
        size_t i = base;
        const float* s0 = (i < GUP_ELEMS) ? gup + i : dp + (i - GUP_ELEMS);
        f32x4 a0 = ntld(s0), b0 = ntld(s0 + 4);
        for (int j = 1; j < CONV_ITERS; ++j) {
            size_t ni = base + (size_t)j * CONV_STRIDE;
            const float* s = (ni < GUP_ELEMS) ? gup + ni : dp + (ni - GUP_ELEMS);
            f32x4 a1 = ntld(s), b1 = ntld(s + 4);
            *reinterpret_cast<sh8*>(wgu + i) = pack8v(a0, b0);
            a0 = a1; b0 = b1; i = ni;
        }
        *reinterpret_cast<sh8*>(wgu + i) = pack8v(a0, b0);
        return;
    }
    int rb = (int)blockIdx.x;

    int wid  = threadIdx.x >> 6;
    int lane = threadIdx.x & 63;
    int t = rb * 4 + wid;

    float4 h[4];
    const float4* xr = reinterpret_cast<const float4*>(X + (size_t)t * DIM);
    #pragma unroll
    for (int c = 0; c < 4; ++c) h[c] = xr[lane + 64 * c];

    float myscore = 0.f;
    for (int e = 0; e < NEXP; ++e) {
        const float4* gr = reinterpret_cast<const float4*>(GW + (size_t)e * DIM);
        float p = 0.f;
        #pragma unroll
        for (int c = 0; c < 4; ++c) {
            float4 g = gr[lane + 64 * c];
            p += h[c].x * g.x + h[c].y * g.y + h[c].z * g.z + h[c].w * g.w;
        }
        #pragma unroll
        for (int o = 32; o; o >>= 1) p += __shfl_xor(p, o);
        if (lane == e) myscore = p;
    }
    float rw = 1.f / (1.f + expf(-myscore));
    float sel = (lane < NEXP) ? rw + bias[lane] : -1e30f;

    float wsum = 0.f;
    int   oi = 0; float ow = 0.f;
    #pragma unroll
    for (int k = 0; k < TOPK; ++k) {
        float v = sel;
        int   idx = (lane < NEXP) ? lane : 9999;
        #pragma unroll
        for (int o = 32; o; o >>= 1) {
            float v2 = __shfl_xor(v, o);
            int   i2 = __shfl_xor(idx, o);
            if (v2 > v || (v2 == v && i2 < idx)) { v = v2; idx = i2; }
        }
        float wk = __shfl(rw, idx);
        wsum += wk;
        if (lane == k)   { oi = idx; ow = wk; }
        if (lane == idx) sel = -1e30f;
    }
    if (lane < TOPK) {
        int gid = t * TOPK + lane;
        topk_idx[gid] = oi;
        topk_w  [gid] = ow / (wsum + 1e-6f);
        int pos = atomicAdd(&cnt[oi], 1);   // order-nondeterministic, consumption is order-invariant
        tlist_c[oi * T_TOK + pos] = t;
        posmap[gid] = pos;
    }
}

// ---------------- Gather: padded tlist (+ optional Xg bf16) ----------------
template<bool DO_XG>
__global__ __launch_bounds__(256) void gather_kernel(
    const float* __restrict__ X, const int* __restrict__ cnt,
    const int* __restrict__ tlist_c,
    short* __restrict__ Xg, int* __restrict__ tlist_p)
{
    int wid = threadIdx.x >> 6, lane = threadIdx.x & 63;
    int r = blockIdx.x * 4 + wid;
    int ts;
    int e = tile_expert(cnt, r >> 7, ts);
    if (e < 0) return;
    int li = r - (ts << 7);
    bool real = li < cnt[e];
    int t = real ? tlist_c[e * T_TOK + li] : 0;
    if (lane == 0) tlist_p[r] = t;
    if (DO_XG) {
        const float4* src = reinterpret_cast<const float4*>(X + (size_t)t * DIM);
        sh8* dst = reinterpret_cast<sh8*>(Xg + (size_t)r * DIM);
        float4 z = make_float4(0.f, 0.f, 0.f, 0.f);
        #pragma unroll
        for (int it = 0; it < 2; ++it) {
            int si = it * 64 + lane;
            float4 a = real ? src[2 * si]     : z;
            float4 b = real ? src[2 * si + 1] : z;
            dst[si] = pack8(a, b);
        }
    }
}

// ---------------- GEMM1: Xg @ Wgu^T (g,u fused), silu, H bf16 ----------------
// m97-classic: 128(M) x 64(N, x2 g/u), BK=64, single-buffered 32KB LDS,
// two barriers/K-step, glds16 staging, T2 swizzle, XCD swizzle.
template<bool A_GLDS, bool W_BF16>
__global__ __launch_bounds__(256, 4) void gemm1_kernel(
    const short* __restrict__ Xg, const float* __restrict__ X,
    const short* __restrict__ Wgu, const float* __restrict__ GUP,
    const int* __restrict__ cnt, const int* __restrict__ tlist_p,
    short* __restrict__ H)
{
    int bid = (blockIdx.x & 7) * (MAXT * 16 / 8) + (blockIdx.x >> 3);
    int mt = bid >> 4;
    int nt = bid & 15;
    int ts;
    int e = tile_expert(cnt, mt, ts);
    if (e < 0) return;
    int m0 = mt * 128, n0 = nt * 64;

    __shared__ short As[128 * 64];
    __shared__ short Bg[64 * 64];
    __shared__ short Bu[64 * 64];

    int tid = threadIdx.x, lane = tid & 63, wv = tid >> 6;
    int wm = (wv >> 1) * 64, wn = (wv & 1) * 32;

    f32x4 accg[4][2] = {};
    f32x4 accu[4][2] = {};

    int swcol = ((lane & 7) ^ (lane >> 3)) * 8;  // pre-swizzled global col (elems)
    const float* xrow = nullptr; int arow = 0, acol = 0;
    if (!A_GLDS) {
        arow = tid >> 1; acol = (tid & 1) * 32;
        xrow = X + (size_t)tlist_p[m0 + arow] * DIM;
    }
    const float *grow = nullptr, *urow = nullptr;
    int brow = tid >> 2, bcol = (tid & 3) * 16;
    if (!W_BF16) {
        grow = GUP + ((size_t)e * 2 * IDIM + n0 + brow) * DIM;
        urow = GUP + ((size_t)e * 2 * IDIM + IDIM + n0 + brow) * DIM;
    }
    const short* gb = Wgu + ((size_t)e * 2 * IDIM + n0) * DIM;
    const short* ub = Wgu + ((size_t)e * 2 * IDIM + IDIM + n0) * DIM;

    auto stage = [&](int k0) {
        if (A_GLDS) {
            #pragma unroll
            for (int j = 0; j < 4; ++j) {
                int ch = wv * 4 + j;
                glds16(Xg + (size_t)(m0 + ch * 8 + (lane >> 3)) * DIM + k0 + swcol, &As[ch * 512]);
            }
        } else {
            #pragma unroll
            for (int j = 0; j < 4; ++j) {
                int c = acol + j * 8;
                float4 a  = *reinterpret_cast<const float4*>(xrow + k0 + c);
                float4 bv = *reinterpret_cast<const float4*>(xrow + k0 + c + 4);
                *reinterpret_cast<sh8*>(&As[arow * 64 + (c ^ ((arow & 7) << 3))]) = pack8(a, bv);
            }
        }
        if (W_BF16) {
            #pragma unroll
            for (int j = 0; j < 2; ++j) {
                int ch = wv * 2 + j;
                glds16(gb + (size_t)(ch * 8 + (lane >> 3)) * DIM + k0 + swcol, &Bg[ch * 512]);
                glds16(ub + (size_t)(ch * 8 + (lane >> 3)) * DIM + k0 + swcol, &Bu[ch * 512]);
            }
        } else {
            #pragma unroll
            for (int j = 0; j < 2; ++j) {
                int c = bcol + j * 8;
                float4 a  = *reinterpret_cast<const float4*>(grow + k0 + c);
                float4 bv = *reinterpret_cast<const float4*>(grow + k0 + c + 4);
                *reinterpret_cast<sh8*>(&Bg[brow * 64 + (c ^ ((brow & 7) << 3))]) = pack8(a, bv);
                a  = *reinterpret_cast<const float4*>(urow + k0 + c);
                bv = *reinterpret_cast<const float4*>(urow + k0 + c + 4);
                *reinterpret_cast<sh8*>(&Bu[brow * 64 + (c ^ ((brow & 7) << 3))]) = pack8(a, bv);
            }
        }
    };

    int swr = (lane & 7) << 3;
    for (int it = 0; it < DIM / 64; ++it) {
        stage(it * 64);
        __syncthreads();
        #pragma unroll
        for (int kk = 0; kk < 64; kk += 32) {
            int ki = (kk + (lane >> 4) * 8) ^ swr;
            sh8 af[4], gf[2], uf[2];
            #pragma unroll
            for (int fm = 0; fm < 4; ++fm)
                af[fm] = *reinterpret_cast<const sh8*>(&As[(wm + fm * 16 + (lane & 15)) * 64 + ki]);
            #pragma unroll
            for (int fn = 0; fn < 2; ++fn) {
                gf[fn] = *reinterpret_cast<const sh8*>(&Bg[(wn + fn * 16 + (lane & 15)) * 64 + ki]);
                uf[fn] = *reinterpret_cast<const sh8*>(&Bu[(wn + fn * 16 + (lane & 15)) * 64 + ki]);
            }
            #pragma unroll
            for (int fm = 0; fm < 4; ++fm)
                #pragma unroll
                for (int fn = 0; fn < 2; ++fn) {
                    accg[fm][fn] = __builtin_amdgcn_mfma_f32_16x16x32_bf16(af[fm], gf[fn], accg[fm][fn], 0, 0, 0);
                    accu[fm][fn] = __builtin_amdgcn_mfma_f32_16x16x32_bf16(af[fm], uf[fn], accu[fm][fn], 0, 0, 0);
                }
        }
        __syncthreads();
    }

    #pragma unroll
    for (int fm = 0; fm < 4; ++fm)
        #pragma unroll
        for (int r = 0; r < 4; ++r) {
            int row = m0 + wm + fm * 16 + (lane >> 4) * 4 + r;
            #pragma unroll
            for (int fn = 0; fn < 2; ++fn) {
                int col = n0 + wn + fn * 16 + (lane & 15);
                float g = accg[fm][fn][r];
                float u = accu[fm][fn][r];
                H[(size_t)row * IDIM + col] = bf(g / (1.f + expf(-g)) * u);
            }
        }
}

// ---------------- GEMM2: H @ Wd^T -> Y (no atomics), m97-classic ----------------
template<bool W_BF16, bool Y_F32>
__global__ __launch_bounds__(256, 4) void gemm2_kernel(
    const short* __restrict__ H, const short* __restrict__ Wd, const float* __restrict__ DP,
    const int* __restrict__ cnt, float* __restrict__ Yf, short* __restrict__ Yb)
{
    int bid = (blockIdx.x & 7) * (MAXT * 8 / 8) + (blockIdx.x >> 3);
    int mt = bid >> 3;
    int nt = bid & 7;
    int ts;
    int e = tile_expert(cnt, mt, ts);
    if (e < 0) return;
    int m0 = mt * 128, n0 = nt * 128;

    __shared__ short As[128 * 64];
    __shared__ short Bs[128 * 64];

    int tid = threadIdx.x, lane = tid & 63, wv = tid >> 6;
    int wm = (wv >> 1) * 64, wn = (wv & 1) * 64;

    f32x4 acc[4][4] = {};

    int swcol = ((lane & 7) ^ (lane >> 3)) * 8;
    const float* drow = nullptr; int brow = 0, bcol = 0;
    if (!W_BF16) {
        brow = tid >> 1; bcol = (tid & 1) * 32;
        drow = DP + ((size_t)e * DIM + n0 + brow) * IDIM;
    }
    const short* db = Wd + ((size_t)e * DIM + n0) * IDIM;

    auto stage = [&](int k0) {
        #pragma unroll
        for (int j = 0; j < 4; ++j) {
            int ch = wv * 4 + j;
            glds16(H + (size_t)(m0 + ch * 8 + (lane >> 3)) * IDIM + k0 + swcol, &As[ch * 512]);
        }
        if (W_BF16) {
            #pragma unroll
            for (int j = 0; j < 4; ++j) {
                int ch = wv * 4 + j;
                glds16(db + (size_t)(ch * 8 + (lane >> 3)) * IDIM + k0 + swcol, &Bs[ch * 512]);
            }
        } else {
            #pragma unroll
            for (int j = 0; j < 4; ++j) {
                int c = bcol + j * 8;
                float4 a  = *reinterpret_cast<const float4*>(drow + k0 + c);
                float4 bv = *reinterpret_cast<const float4*>(drow + k0 + c + 4);
                *reinterpret_cast<sh8*>(&Bs[brow * 64 + (c ^ ((brow & 7) << 3))]) = pack8(a, bv);
            }
        }
    };

    int swr = (lane & 7) << 3;
    for (int it = 0; it < IDIM / 64; ++it) {
        stage(it * 64);
        __syncthreads();
        #pragma unroll
        for (int kk = 0; kk < 64; kk += 32) {
            int ki = (kk + (lane >> 4) * 8) ^ swr;
            sh8 af[4], bq[4];
            #pragma unroll
            for (int fm = 0; fm < 4; ++fm)
                af[fm] = *reinterpret_cast<const sh8*>(&As[(wm + fm * 16 + (lane & 15)) * 64 + ki]);
            #pragma unroll
            for (int fn = 0; fn < 4; ++fn)
                bq[fn] = *reinterpret_cast<const sh8*>(&Bs[(wn + fn * 16 + (lane & 15)) * 64 + ki]);
            #pragma unroll
            for (int fm = 0; fm < 4; ++fm)
                #pragma unroll
                for (int fn = 0; fn < 4; ++fn)
                    acc[fm][fn] = __builtin_amdgcn_mfma_f32_16x16x32_bf16(af[fm], bq[fn], acc[fm][fn], 0, 0, 0);
        }
        __syncthreads();
    }

    #pragma unroll
    for (int fm = 0; fm < 4; ++fm)
        #pragma unroll
        for (int r = 0; r < 4; ++r) {
            int row = m0 + wm + fm * 16 + (lane >> 4) * 4 + r;
            #pragma unroll
            for (int fn = 0; fn < 4; ++fn) {
                int col = n0 + wn + fn * 16 + (lane & 15);
                if (Y_F32) Yf[(size_t)row * DIM + col] = acc[fm][fn][r];
                else       Yb[(size_t)row * DIM + col] = bf(acc[fm][fn][r]);
            }
        }
}

// ---------------- Combine: out[t] = sum_k w_k * Y[row(t,k)] ----------------
template<bool Y_F32>
__global__ __launch_bounds__(256) void combine_kernel(
    const float* __restrict__ Yf, const short* __restrict__ Yb,
    const int* __restrict__ cnt, const int* __restrict__ topk_idx,
    const float* __restrict__ topk_w, const int* __restrict__ posmap,
    float* __restrict__ out)
{
    int t = blockIdx.x;
    int d = threadIdx.x * 4;
    int es[TOPK], rows[TOPK];
    #pragma unroll
    for (int k = 0; k < TOPK; ++k) es[k] = topk_idx[t * TOPK + k];
    int p = 0;
    #pragma unroll
    for (int i = 0; i < NEXP; ++i) {
        #pragma unroll
        for (int k = 0; k < TOPK; ++k)
            if (es[k] == i) rows[k] = p + posmap[t * TOPK + k];
        p += ((cnt[i] + 127) >> 7) << 7;
    }
    float4 acc = make_float4(0.f, 0.f, 0.f, 0.f);
    #pragma unroll
    for (int k = 0; k < TOPK; ++k) {
        float w = topk_w[t * TOPK + k];
        if (Y_F32) {
            float4 y = *reinterpret_cast<const float4*>(Yf + (size_t)rows[k] * DIM + d);
            acc.x += w * y.x; acc.y += w * y.y; acc.z += w * y.z; acc.w += w * y.w;
        } else {
            short4 y = *reinterpret_cast<const short4*>(Yb + (size_t)rows[k] * DIM + d);
            acc.x += w * bf2f(y.x); acc.y += w * bf2f(y.y);
            acc.z += w * bf2f(y.z); acc.w += w * bf2f(y.w);
        }
    }
    *reinterpret_cast<float4*>(out + (size_t)t * DIM + d) = acc;
}

// ---------------- launch ----------------
extern "C" void kernel_launch(void* const* d_in, const int* in_sizes, int n_in,
                              void* d_out, int out_size, void* d_ws, size_t ws_size,
                              hipStream_t stream)
{
    const float* X    = (const float*)d_in[0];
    const float* GW   = (const float*)d_in[1];
    const float* GUP  = (const float*)d_in[2];
    const float* DP   = (const float*)d_in[3];
    const float* BIAS = (const float*)d_in[4];
    float* out = (float*)d_out;

    char* ws = (char*)d_ws;
    int*   cnt      = (int*)ws;                       // 128 B
    int*   topk_idx = (int*)(ws + (4u   << 10));      // 64 KB
    float* topk_w   = (float*)(ws + (68u  << 10));    // 64 KB
    int*   posmap   = (int*)(ws + (132u << 10));      // 64 KB
    int*   tlist_c  = (int*)(ws + (196u << 10));      // 512 KB
    int*   tlist_p  = (int*)(ws + (708u << 10));      // 80 KB

    constexpr size_t OFF_H   = 2ull << 20;
    constexpr size_t SZ_ROWS = (size_t)RPAD * IDIM * 2;             // 40 MB
    constexpr size_t OFF_XG  = OFF_H + SZ_ROWS;
    constexpr size_t OFF_WGU = OFF_XG + SZ_ROWS;
    constexpr size_t OFF_WD  = OFF_WGU + GUP_ELEMS * 2;
    constexpr size_t END_ALL = OFF_WD + (ALL_ELEMS - GUP_ELEMS) * 2; // ~287 MB
    constexpr size_t SZ_YF   = (size_t)RPAD * DIM * 4;              // 80 MB

    short* H   = (short*)(ws + OFF_H);
    short* Xg  = (short*)(ws + OFF_XG);
    short* Wgu = (short*)(ws + OFF_WGU);
    short* Wd  = (short*)(ws + OFF_WD);
    float* Yf  = (float*)(ws + END_ALL);
    short* Yb  = Xg;                                  // Xg dead after gemm1

    bool t1   = ws_size >= END_ALL;
    bool t2   = ws_size >= OFF_WGU;
    bool yf32 = ws_size >= END_ALL + SZ_YF;

    (void)hipMemsetAsync(cnt, 0, 128, stream);

    if (t1) front_kernel<true ><<<ROUTER_BLOCKS + CONV_BLOCKS, 256, 0, stream>>>(
        X, GW, BIAS, GUP, DP, Wgu, topk_idx, topk_w, cnt, tlist_c, posmap);
    else    front_kernel<false><<<ROUTER_BLOCKS, 256, 0, stream>>>(
        X, GW, BIAS, GUP, DP, Wgu, topk_idx, topk_w, cnt, tlist_c, posmap);

    if (t2) gather_kernel<true ><<<RPAD / 4, 256, 0, stream>>>(X, cnt, tlist_c, Xg, tlist_p);
    else    gather_kernel<false><<<RPAD / 4, 256, 0, stream>>>(X, cnt, tlist_c, Xg, tlist_p);

    int g1 = MAXT * 16;   // 2560, %8==0 for XCD swizzle
    if (t1)      gemm1_kernel<true , true ><<<g1, 256, 0, stream>>>(Xg, X, Wgu, GUP, cnt, tlist_p, H);
    else if (t2) gemm1_kernel<true , false><<<g1, 256, 0, stream>>>(Xg, X, Wgu, GUP, cnt, tlist_p, H);
    else         gemm1_kernel<false, false><<<g1, 256, 0, stream>>>(Xg, X, Wgu, GUP, cnt, tlist_p, H);

    int g2 = MAXT * 8;    // 1280, %8==0
    if (t1) {
        if (yf32) gemm2_kernel<true , true ><<<g2, 256, 0, stream>>>(H, Wd, DP, cnt, Yf, Yb);
        else      gemm2_kernel<true , false><<<g2, 256, 0, stream>>>(H, Wd, DP, cnt, Yf, Yb);
    } else {
        if (yf32) gemm2_kernel<false, true ><<<g2, 256, 0, stream>>>(H, Wd, DP, cnt, Yf, Yb);
        else      gemm2_kernel<false, false><<<g2, 256, 0, stream>>>(H, Wd, DP, cnt, Yf, Yb);
    }

    if (yf32) combine_kernel<true ><<<T_TOK, 256, 0, stream>>>(Yf, Yb, cnt, topk_idx, topk_w, posmap, out);
    else      combine_kernel<false><<<T_TOK, 256, 0, stream>>>(Yf, Yb, cnt, topk_idx, topk_w, posmap, out);
}